// Round 6
// baseline (431.889 us; speedup 1.0000x reference)
//
#include <hip/hip_runtime.h>
#include <stdint.h>

#define SEQ    4096
#define HID    2048
#define NQKV   6144
#define QKW    4096   // width of the QK row-major buffer (Q | K)
#define NH     16
#define HD     128
#define SCALE  0.08838834764831845f
#define GQC    32     // split-KV chunks for global-query kernel (128 kv each)

typedef unsigned short u16;
typedef __attribute__((ext_vector_type(8))) short bf16x8;
typedef __attribute__((ext_vector_type(4))) float f32x4;

__device__ __forceinline__ u16 f2bf(float f) {
  union { float f; unsigned u; } v; v.f = f;
  unsigned r = v.u + 0x7FFFu + ((v.u >> 16) & 1u);
  return (u16)(r >> 16);
}

__device__ __forceinline__ float bf2f(u16 b) {
  union { unsigned u; float f; } c; c.u = ((unsigned)b) << 16; return c.f;
}

__device__ __forceinline__ void async16(const u16* g, u16* l) {
  __builtin_amdgcn_global_load_lds(
      (const __attribute__((address_space(1))) unsigned int*)g,
      (__attribute__((address_space(3))) unsigned int*)l, 16, 0, 0);
}

// ---------------- fp32 -> bf16 convert (X) ----------------
__global__ __launch_bounds__(256) void cvt_f32_bf16(const float* __restrict__ in,
                                                    u16* __restrict__ out, int n4) {
  int i = blockIdx.x * 256 + threadIdx.x;
  if (i >= n4) return;
  float4 v = ((const float4*)in)[i];
  ushort4 o;
  o.x = f2bf(v.x); o.y = f2bf(v.y); o.z = f2bf(v.z); o.w = f2bf(v.w);
  ((ushort4*)out)[i] = o;
}

// ------ fused weight transposes: z selects {Wq,Wk,Wv}->Wcat, Wo->Wot ------
// LDS stride 68 u16 (136 B): phase-2 lane-column reads hit bank 2*lane mod 32
// (2-way = free). The old stride 72 (144 B) gave bank 8*lane mod 32 = 4-way.
__global__ __launch_bounds__(256) void transpose_w4(const float* __restrict__ W0,
                                                    const float* __restrict__ W1,
                                                    const float* __restrict__ W2,
                                                    const float* __restrict__ W3,
                                                    u16* __restrict__ Wcat,
                                                    u16* __restrict__ Wot) {
  __shared__ __align__(16) u16 Ts[64 * 68];
  const int n0 = blockIdx.x * 64;
  const int k0 = blockIdx.y * 64;
  const int z = blockIdx.z;
  const float* W = (z == 0) ? W0 : (z == 1) ? W1 : (z == 2) ? W2 : W3;
  u16* Wt = (z < 3) ? (Wcat + (size_t)z * 2048 * 2048) : Wot;
  const int t = threadIdx.x;
#pragma unroll
  for (int p = 0; p < 4; ++p) {
    int f = (t + p * 256) * 4;
    int r = f >> 6, c = f & 63;            // r=k_local, c=n_local
    float4 v = *(const float4*)&W[(size_t)(k0 + r) * 2048 + n0 + c];
    ushort4 o; o.x = f2bf(v.x); o.y = f2bf(v.y); o.z = f2bf(v.z); o.w = f2bf(v.w);
    *(ushort4*)&Ts[r * 68 + c] = o;
  }
  __syncthreads();
#pragma unroll
  for (int p = 0; p < 4; ++p) {
    int g = (t + p * 256) * 4;
    int r = g >> 6, c = g & 63;            // r=n_local, c=k_local
    ushort4 o;
    o.x = Ts[(c + 0) * 68 + r];
    o.y = Ts[(c + 1) * 68 + r];
    o.z = Ts[(c + 2) * 68 + r];
    o.w = Ts[(c + 3) * 68 + r];
    *(ushort4*)&Wt[(size_t)(n0 + r) * 2048 + k0 + c] = o;
  }
}

// ---------------- GEMM: C[m][n] = sum_k A[m][k] * Bt[n][k]  (bf16 in, fp32 acc) ----------------
// 16x16x32 MFMA, 128x128 block (m97 structure — measured floor for this shape;
// 32x32x16 frags triple LDS conflicts and are net-neutral/worse, R4/R5).
// WVT: n0>=4096 blocks are the V-projection, written DIRECTLY in VT[h][d][s]
// layout (C-layout gives 4 consecutive m=s per reg group -> 8B packed stores).
template <typename OutT, bool WVT>
__global__ __launch_bounds__(256) void gemm_bt(const u16* __restrict__ A,
                                               const u16* __restrict__ B,
                                               OutT* __restrict__ C,
                                               u16* __restrict__ VTout,
                                               int K, int ldc) {
  __shared__ __align__(16) u16 As[128 * 32];
  __shared__ __align__(16) u16 Bs[128 * 32];
  const int m0 = blockIdx.y * 128;
  const int n0 = blockIdx.x * 128;
  const int tid = threadIdx.x;
  const int wid = tid >> 6;
  const int lane = tid & 63;
  const int wm = wid & 1, wn = wid >> 1;
  const int l15 = lane & 15, g4 = lane >> 4;

  const int srow = wid * 32 + (lane >> 2);
  const int scol = (lane & 3) * 8;

  f32x4 acc[4][4] = {};

  const u16* pa0 = &A[(size_t)(m0 + srow) * K + scol];
  const u16* pa1 = &A[(size_t)(m0 + srow + 16) * K + scol];
  const u16* pb0 = &B[(size_t)(n0 + srow) * K + scol];
  const u16* pb1 = &B[(size_t)(n0 + srow + 16) * K + scol];
  u16* la0 = &As[(wid * 32) * 32];
  u16* la1 = &As[(wid * 32 + 16) * 32];
  u16* lb0 = &Bs[(wid * 32) * 32];
  u16* lb1 = &Bs[(wid * 32 + 16) * 32];

  for (int kt = 0; kt < K; kt += 32) {
    __syncthreads();
    async16(pa0 + kt, la0);
    async16(pa1 + kt, la1);
    async16(pb0 + kt, lb0);
    async16(pb1 + kt, lb1);
    __syncthreads();
    bf16x8 af[4], bfr[4];
#pragma unroll
    for (int i = 0; i < 4; ++i)
      af[i] = *(const bf16x8*)&As[(wm * 64 + i * 16 + l15) * 32 + g4 * 8];
#pragma unroll
    for (int i = 0; i < 4; ++i)
      bfr[i] = *(const bf16x8*)&Bs[(wn * 64 + i * 16 + l15) * 32 + g4 * 8];
#pragma unroll
    for (int mi = 0; mi < 4; ++mi)
#pragma unroll
      for (int ni = 0; ni < 4; ++ni)
        acc[mi][ni] = __builtin_amdgcn_mfma_f32_16x16x32_bf16(af[mi], bfr[ni], acc[mi][ni], 0, 0, 0);
  }

  // C/D layout (m89): col = lane&15, row = (lane>>4)*4 + reg
  if (WVT && n0 >= QKW) {
#pragma unroll
    for (int mi = 0; mi < 4; ++mi)
#pragma unroll
      for (int ni = 0; ni < 4; ++ni) {
        const int nv = n0 - QKW + wn * 64 + ni * 16 + l15;
        const int hh = nv >> 7, dd = nv & 127;
        u16* base = &VTout[((size_t)hh * HD + dd) * SEQ];
        const int mb = m0 + wm * 64 + mi * 16 + g4 * 4;
        u16 pk[4];
#pragma unroll
        for (int r = 0; r < 4; ++r) pk[r] = f2bf(acc[mi][ni][r]);
        *(uint2*)&base[mb] = *(uint2*)pk;
      }
  } else {
#pragma unroll
    for (int mi = 0; mi < 4; ++mi)
#pragma unroll
      for (int ni = 0; ni < 4; ++ni) {
        const int n = n0 + wn * 64 + ni * 16 + l15;
#pragma unroll
        for (int r = 0; r < 4; ++r) {
          const int m = m0 + wm * 64 + mi * 16 + g4 * 4 + r;
          float v = acc[mi][ni][r];
          if constexpr (sizeof(OutT) == 2) {
            C[(size_t)m * ldc + n] = (OutT)f2bf(v);
          } else {
            C[(size_t)m * ldc + n] = v;
          }
        }
      }
  }
}

// ---------------- flash attention (local window + global-kv only) ----------------
__global__ __launch_bounds__(256, 3) void attn_kernel(const u16* __restrict__ qk,
                                                      const u16* __restrict__ vt,
                                                      u16* __restrict__ out) {
  __shared__ __align__(16) u16 Ks[64 * 128];   // swizzled [kv][d]
  __shared__ __align__(16) u16 VTs[128 * 64];  // swizzled [d][kv]
  __shared__ __align__(16) u16 Ps[64 * 64];    // swizzled [q][kv], wave-private rows
  const int q0 = blockIdx.x * 64;
  const int h = blockIdx.y;
  const int tid = threadIdx.x;
  const int w = tid >> 6;
  const int lane = tid & 63;
  const int l15 = lane & 15, g4 = lane >> 4;
  const int l7 = l15 & 7;

  // Q fragments in registers
  bf16x8 qf[4];
  {
    const u16* qrow = &qk[(size_t)(q0 + w * 16 + l15) * QKW + h * HD + g4 * 8];
#pragma unroll
    for (int kk = 0; kk < 4; ++kk) qf[kk] = *(const bf16x8*)&qrow[kk * 32];
  }

  float m_run = -1e30f, l_run = 0.f;
  f32x4 o[8] = {};

  int lo = q0 - 255;
  int lo_blk = (lo < 0) ? 0 : (lo >> 6);
  int hi_blk = (q0 + 318) >> 6;
  if (hi_blk > 63) hi_blk = 63;
  const int extra = (lo_blk > 0) ? 1 : 0;     // kb=0 pre-pass for global kv cols
  const int nsteps = hi_blk - lo_blk + 1 + extra;

  for (int step = 0; step < nsteps; ++step) {
    const int kb = (extra && step == 0) ? 0 : (lo_blk + step - extra);
    const int kv0 = kb * 64;
    __syncthreads();
    // stage K tile [64 kv][128 d], swizzled
#pragma unroll
    for (int p = 0; p < 4; ++p) {
      int id = p * 256 + tid;
      int r = id >> 4, c8 = id & 15;
      uint4 v = *(const uint4*)&qk[(size_t)(kv0 + r) * QKW + 2048 + h * HD + c8 * 8];
      *(uint4*)&Ks[r * 128 + ((c8 ^ (r & 15)) * 8)] = v;
    }
    // stage V^T tile [128 d][64 kv], swizzled
#pragma unroll
    for (int p = 0; p < 4; ++p) {
      int id = p * 256 + tid;
      int r = id >> 3, c8 = id & 7;
      uint4 v = *(const uint4*)&vt[(size_t)h * (HD * SEQ) + (size_t)r * SEQ + kv0 + c8 * 8];
      *(uint4*)&VTs[r * 64 + ((c8 ^ (r & 7)) * 8)] = v;
    }
    __syncthreads();

    // S^T = K @ Q^T
    f32x4 st[4] = {};
#pragma unroll
    for (int kk = 0; kk < 4; ++kk) {
#pragma unroll
      for (int t4 = 0; t4 < 4; ++t4) {
        bf16x8 ak = *(const bf16x8*)&Ks[(t4 * 16 + l15) * 128 + (((kk * 4 + g4) ^ l15) * 8)];
        st[t4] = __builtin_amdgcn_mfma_f32_16x16x32_bf16(ak, qf[kk], st[t4], 0, 0, 0);
      }
    }

    // online softmax per q column
    const int q = q0 + w * 16 + l15;
    float pv[4][4];
    float cmax = -1e30f;
#pragma unroll
    for (int t4 = 0; t4 < 4; ++t4)
#pragma unroll
      for (int r = 0; r < 4; ++r) {
        int kv = kv0 + t4 * 16 + g4 * 4 + r;
        int dq = q - kv; if (dq < 0) dq = -dq;
        bool ok = (dq < 256) || (kv < 16);
        float s = ok ? st[t4][r] * SCALE : -1e30f;
        pv[t4][r] = s;
        cmax = fmaxf(cmax, s);
      }
    cmax = fmaxf(cmax, __shfl_xor(cmax, 16, 64));
    cmax = fmaxf(cmax, __shfl_xor(cmax, 32, 64));
    float mnew = fmaxf(m_run, cmax);
    float csum = 0.f;
#pragma unroll
    for (int t4 = 0; t4 < 4; ++t4)
#pragma unroll
      for (int r = 0; r < 4; ++r) {
        float p = __expf(pv[t4][r] - mnew);
        pv[t4][r] = p;
        csum += p;
      }
    csum += __shfl_xor(csum, 16, 64);
    csum += __shfl_xor(csum, 32, 64);
    float alpha = __expf(m_run - mnew);
    m_run = mnew;
    l_run = l_run * alpha + csum;

    // write P (bf16) into wave-private swizzled rows
#pragma unroll
    for (int t4 = 0; t4 < 4; ++t4) {
      u16 pk[4];
#pragma unroll
      for (int r = 0; r < 4; ++r) pk[r] = f2bf(pv[t4][r]);
      int c8 = t4 * 2 + (g4 >> 1);
      *(uint2*)&Ps[(w * 16 + l15) * 64 + ((c8 ^ l7) * 8) + (g4 & 1) * 4] = *(uint2*)pk;
    }

    // rescale O accumulator
    float al[4];
#pragma unroll
    for (int r = 0; r < 4; ++r) al[r] = __shfl(alpha, g4 * 4 + r, 64);
#pragma unroll
    for (int nt = 0; nt < 8; ++nt)
#pragma unroll
      for (int r = 0; r < 4; ++r) o[nt][r] *= al[r];

    // O += P @ V (Ps is wave-private; no barrier needed)
#pragma unroll
    for (int ks = 0; ks < 2; ++ks) {
      bf16x8 ap = *(const bf16x8*)&Ps[(w * 16 + l15) * 64 + (((ks * 4 + g4) ^ l7) * 8)];
#pragma unroll
      for (int nt = 0; nt < 8; ++nt) {
        bf16x8 bv = *(const bf16x8*)&VTs[(nt * 16 + l15) * 64 + (((ks * 4 + g4) ^ l7) * 8)];
        o[nt] = __builtin_amdgcn_mfma_f32_16x16x32_bf16(ap, bv, o[nt], 0, 0, 0);
      }
    }
  }

  // finalize
  float lr[4];
#pragma unroll
  for (int r = 0; r < 4; ++r) lr[r] = 1.f / __shfl(l_run, g4 * 4 + r, 64);
#pragma unroll
  for (int nt = 0; nt < 8; ++nt)
#pragma unroll
    for (int r = 0; r < 4; ++r) {
      const int m = q0 + w * 16 + g4 * 4 + r;
      if (m < 16) continue;
      const int n = h * HD + nt * 16 + l15;
      out[(size_t)m * HID + n] = f2bf(o[nt][r] * lr[r]);
    }
}

// ---------------- global queries (q<16): split-KV VALU flash, partials ----------------
__global__ __launch_bounds__(256) void attn_global(const u16* __restrict__ qk,
                                                   const u16* __restrict__ vt,
                                                   float* __restrict__ Opart,
                                                   float* __restrict__ MLpart) {
  __shared__ __align__(16) u16 Ks[64 * 136];
  __shared__ __align__(16) u16 Vs[64 * 136];
  const int chunk = blockIdx.x, h = blockIdx.y;
  const int t = threadIdx.x;
  const int q = t >> 4, dg = t & 15;

  float qr[8];
  {
    bf16x8 v = *(const bf16x8*)&qk[(size_t)q * QKW + h * HD + dg * 8];
#pragma unroll
    for (int j = 0; j < 8; ++j) qr[j] = bf2f((u16)v[j]);
  }
  float m_run = -1e30f, l_run = 0.f, o[8] = {};
  const int kvbase = chunk * (SEQ / GQC);

  for (int st = 0; st < (SEQ / GQC) / 64; ++st) {
    const int kv0 = kvbase + st * 64;
    __syncthreads();
    // K rows
#pragma unroll
    for (int p = 0; p < 4; ++p) {
      int f = (t + p * 256) * 8;
      int r = f >> 7, c = f & 127;
      *(uint4*)&Ks[r * 136 + c] = *(const uint4*)&qk[(size_t)(kv0 + r) * QKW + 2048 + h * HD + c];
    }
    // V via transpose from VT
#pragma unroll
    for (int p = 0; p < 4; ++p) {
      int id = p * 256 + t;
      int d = id >> 3, c8 = id & 7;
      uint4 v = *(const uint4*)&vt[(size_t)h * (HD * SEQ) + (size_t)d * SEQ + kv0 + c8 * 8];
      const u16* pv16 = (const u16*)&v;
#pragma unroll
      for (int j = 0; j < 8; ++j) Vs[(c8 * 8 + j) * 136 + d] = pv16[j];
    }
    __syncthreads();
    for (int kv = 0; kv < 64; ++kv) {
      bf16x8 kr = *(const bf16x8*)&Ks[kv * 136 + dg * 8];
      float s = 0.f;
#pragma unroll
      for (int j = 0; j < 8; ++j) s += qr[j] * bf2f((u16)kr[j]);
      s += __shfl_xor(s, 1, 64); s += __shfl_xor(s, 2, 64);
      s += __shfl_xor(s, 4, 64); s += __shfl_xor(s, 8, 64);
      s *= SCALE;
      float mnew = fmaxf(m_run, s);
      float alpha = __expf(m_run - mnew);
      float p = __expf(s - mnew);
      m_run = mnew;
      l_run = l_run * alpha + p;
      bf16x8 vr = *(const bf16x8*)&Vs[kv * 136 + dg * 8];
#pragma unroll
      for (int j = 0; j < 8; ++j) o[j] = o[j] * alpha + p * bf2f((u16)vr[j]);
    }
  }
  float* op = &Opart[(((size_t)h * GQC + chunk) * 16 + q) * HD + dg * 8];
#pragma unroll
  for (int j = 0; j < 8; ++j) op[j] = o[j];
  if (dg == 0) {
    float* ml = &MLpart[(((size_t)h * GQC + chunk) * 16 + q) * 2];
    ml[0] = m_run; ml[1] = l_run;
  }
}

// ---------------- combine split-KV partials, write rows 0-15 of AttnO ----------------
__global__ __launch_bounds__(256) void attn_gred(const float* __restrict__ Opart,
                                                 const float* __restrict__ MLpart,
                                                 u16* __restrict__ out) {
  const int h = blockIdx.x;
  const int t = threadIdx.x;
  const int q = t >> 4, dg = t & 15;
  float M = -1e30f;
  for (int c = 0; c < GQC; ++c)
    M = fmaxf(M, MLpart[(((size_t)h * GQC + c) * 16 + q) * 2]);
  float L = 0.f, o[8] = {};
  for (int c = 0; c < GQC; ++c) {
    const float* ml = &MLpart[(((size_t)h * GQC + c) * 16 + q) * 2];
    float e = __expf(ml[0] - M);
    L += e * ml[1];
    const float* op = &Opart[(((size_t)h * GQC + c) * 16 + q) * HD + dg * 8];
#pragma unroll
    for (int j = 0; j < 8; ++j) o[j] += e * op[j];
  }
  float inv = 1.f / L;
  u16 tmp[8];
#pragma unroll
  for (int j = 0; j < 8; ++j) tmp[j] = f2bf(o[j] * inv);
  *(uint4*)&out[(size_t)q * HID + h * HD + dg * 8] = *(uint4*)tmp;
}

extern "C" void kernel_launch(void* const* d_in, const int* in_sizes, int n_in,
                              void* d_out, int out_size, void* d_ws, size_t ws_size,
                              hipStream_t stream) {
  const float* X  = (const float*)d_in[0];
  const float* Wq = (const float*)d_in[1];
  const float* Wk = (const float*)d_in[2];
  const float* Wv = (const float*)d_in[3];
  const float* Wo = (const float*)d_in[4];
  float* out = (float*)d_out;

  // workspace layout (96 MiB, lifetime-aliased):
  //  [0,16M):   Xbf   (dead after QKV GEMM)
  //  [16M,40M): Wcat  (dead after QKV GEMM) -> [16M,32M) AttnO, [32M,36M) Opart,
  //                                            [36M,~36.1M) MLpart
  //  [40M,72M): QK row-major [4096][4096] bf16 (Q | K)
  //  [72M,88M): VT[h][d][s] bf16 (written directly by QKV GEMM epilogue)
  //  [88M,96M): Wo^T bf16
  char* ws = (char*)d_ws;
  u16* Xbf    = (u16*)(ws);
  u16* Wcat   = (u16*)(ws + (size_t)(16 << 20));
  u16* AttnO  = (u16*)(ws + (size_t)(16 << 20));     // alias Wcat (post-GEMM)
  float* Opart  = (float*)(ws + (size_t)(32 << 20));
  float* MLpart = (float*)(ws + (size_t)(36 << 20));
  u16* QK     = (u16*)(ws + (size_t)(40 << 20));
  u16* VT     = (u16*)(ws + (size_t)(72 << 20));
  u16* Wot    = (u16*)(ws + (size_t)(88 << 20));

  // 1) X -> bf16
  cvt_f32_bf16<<<dim3(8192), dim3(256), 0, stream>>>(X, Xbf, (SEQ * HID) / 4);
  // 2) weight transposes (fp32 [k][n] -> bf16 [n][k]), one launch
  transpose_w4<<<dim3(32, 32, 4), 256, 0, stream>>>(Wq, Wk, Wv, Wo, Wcat, Wot);
  // 3) fused QKV GEMM: Q,K -> QK row-major; V -> VT transposed
  gemm_bt<u16, true><<<dim3(48, 32), 256, 0, stream>>>(Xbf, Wcat, QK, VT, HID, QKW);
  // 4) global queries: split-KV partials
  attn_global<<<dim3(GQC, NH), 256, 0, stream>>>(QK, VT, Opart, MLpart);
  // 5) local attention (writes rows 16..4095)
  attn_kernel<<<dim3(64, 16), 256, 0, stream>>>(QK, VT, AttnO);
  // 6) combine global-query partials (writes rows 0..15)
  attn_gred<<<dim3(NH), 256, 0, stream>>>(Opart, MLpart, AttnO);
  // 7) output projection -> fp32 out
  gemm_bt<float, false><<<dim3(16, 32), 256, 0, stream>>>(AttnO, Wot, out, nullptr, HID, HID);
}

// Round 7
// 431.180 us; speedup vs baseline: 1.0016x; 1.0016x over previous
//
#include <hip/hip_runtime.h>
#include <stdint.h>

#define SEQ    4096
#define HID    2048
#define NQKV   6144
#define QKW    4096   // width of the QK row-major buffer (Q | K)
#define NH     16
#define HD     128
#define SCALE  0.08838834764831845f
#define GQC    32     // split-KV chunks for global-query kernel (128 kv each)

typedef unsigned short u16;
typedef __attribute__((ext_vector_type(8))) short bf16x8;
typedef __attribute__((ext_vector_type(4))) float f32x4;

__device__ __forceinline__ u16 f2bf(float f) {
  union { float f; unsigned u; } v; v.f = f;
  unsigned r = v.u + 0x7FFFu + ((v.u >> 16) & 1u);
  return (u16)(r >> 16);
}

__device__ __forceinline__ float bf2f(u16 b) {
  union { unsigned u; float f; } c; c.u = ((unsigned)b) << 16; return c.f;
}

__device__ __forceinline__ void async16(const u16* g, u16* l) {
  __builtin_amdgcn_global_load_lds(
      (const __attribute__((address_space(1))) unsigned int*)g,
      (__attribute__((address_space(3))) unsigned int*)l, 16, 0, 0);
}

// ---------------- fp32 -> bf16 convert (X) ----------------
__global__ __launch_bounds__(256) void cvt_f32_bf16(const float* __restrict__ in,
                                                    u16* __restrict__ out, int n4) {
  int i = blockIdx.x * 256 + threadIdx.x;
  if (i >= n4) return;
  float4 v = ((const float4*)in)[i];
  ushort4 o;
  o.x = f2bf(v.x); o.y = f2bf(v.y); o.z = f2bf(v.z); o.w = f2bf(v.w);
  ((ushort4*)out)[i] = o;
}

// ------ fused weight transposes: z selects {Wq,Wk,Wv}->Wcat, Wo->Wot ------
__global__ __launch_bounds__(256) void transpose_w4(const float* __restrict__ W0,
                                                    const float* __restrict__ W1,
                                                    const float* __restrict__ W2,
                                                    const float* __restrict__ W3,
                                                    u16* __restrict__ Wcat,
                                                    u16* __restrict__ Wot) {
  __shared__ __align__(16) u16 Ts[64 * 68];
  const int n0 = blockIdx.x * 64;
  const int k0 = blockIdx.y * 64;
  const int z = blockIdx.z;
  const float* W = (z == 0) ? W0 : (z == 1) ? W1 : (z == 2) ? W2 : W3;
  u16* Wt = (z < 3) ? (Wcat + (size_t)z * 2048 * 2048) : Wot;
  const int t = threadIdx.x;
#pragma unroll
  for (int p = 0; p < 4; ++p) {
    int f = (t + p * 256) * 4;
    int r = f >> 6, c = f & 63;            // r=k_local, c=n_local
    float4 v = *(const float4*)&W[(size_t)(k0 + r) * 2048 + n0 + c];
    ushort4 o; o.x = f2bf(v.x); o.y = f2bf(v.y); o.z = f2bf(v.z); o.w = f2bf(v.w);
    *(ushort4*)&Ts[r * 68 + c] = o;
  }
  __syncthreads();
#pragma unroll
  for (int p = 0; p < 4; ++p) {
    int g = (t + p * 256) * 4;
    int r = g >> 6, c = g & 63;            // r=n_local, c=k_local
    ushort4 o;
    o.x = Ts[(c + 0) * 68 + r];
    o.y = Ts[(c + 1) * 68 + r];
    o.z = Ts[(c + 2) * 68 + r];
    o.w = Ts[(c + 3) * 68 + r];
    *(ushort4*)&Wt[(size_t)(n0 + r) * 2048 + k0 + c] = o;
  }
}

// ---------------- GEMM: C[m][n] = sum_k A[m][k] * Bt[n][k]  (bf16 in, fp32 acc) ----------------
// 16x16x32 MFMA, 128x128 block (m97 structure — measured floor for this shape).
template <typename OutT, bool WVT>
__global__ __launch_bounds__(256) void gemm_bt(const u16* __restrict__ A,
                                               const u16* __restrict__ B,
                                               OutT* __restrict__ C,
                                               u16* __restrict__ VTout,
                                               int K, int ldc) {
  __shared__ __align__(16) u16 As[128 * 32];
  __shared__ __align__(16) u16 Bs[128 * 32];
  const int m0 = blockIdx.y * 128;
  const int n0 = blockIdx.x * 128;
  const int tid = threadIdx.x;
  const int wid = tid >> 6;
  const int lane = tid & 63;
  const int wm = wid & 1, wn = wid >> 1;
  const int l15 = lane & 15, g4 = lane >> 4;

  const int srow = wid * 32 + (lane >> 2);
  const int scol = (lane & 3) * 8;

  f32x4 acc[4][4] = {};

  const u16* pa0 = &A[(size_t)(m0 + srow) * K + scol];
  const u16* pa1 = &A[(size_t)(m0 + srow + 16) * K + scol];
  const u16* pb0 = &B[(size_t)(n0 + srow) * K + scol];
  const u16* pb1 = &B[(size_t)(n0 + srow + 16) * K + scol];
  u16* la0 = &As[(wid * 32) * 32];
  u16* la1 = &As[(wid * 32 + 16) * 32];
  u16* lb0 = &Bs[(wid * 32) * 32];
  u16* lb1 = &Bs[(wid * 32 + 16) * 32];

  for (int kt = 0; kt < K; kt += 32) {
    __syncthreads();
    async16(pa0 + kt, la0);
    async16(pa1 + kt, la1);
    async16(pb0 + kt, lb0);
    async16(pb1 + kt, lb1);
    __syncthreads();
    bf16x8 af[4], bfr[4];
#pragma unroll
    for (int i = 0; i < 4; ++i)
      af[i] = *(const bf16x8*)&As[(wm * 64 + i * 16 + l15) * 32 + g4 * 8];
#pragma unroll
    for (int i = 0; i < 4; ++i)
      bfr[i] = *(const bf16x8*)&Bs[(wn * 64 + i * 16 + l15) * 32 + g4 * 8];
#pragma unroll
    for (int mi = 0; mi < 4; ++mi)
#pragma unroll
      for (int ni = 0; ni < 4; ++ni)
        acc[mi][ni] = __builtin_amdgcn_mfma_f32_16x16x32_bf16(af[mi], bfr[ni], acc[mi][ni], 0, 0, 0);
  }

  // C/D layout (m89): col = lane&15, row = (lane>>4)*4 + reg
  if (WVT && n0 >= QKW) {
#pragma unroll
    for (int mi = 0; mi < 4; ++mi)
#pragma unroll
      for (int ni = 0; ni < 4; ++ni) {
        const int nv = n0 - QKW + wn * 64 + ni * 16 + l15;
        const int hh = nv >> 7, dd = nv & 127;
        u16* base = &VTout[((size_t)hh * HD + dd) * SEQ];
        const int mb = m0 + wm * 64 + mi * 16 + g4 * 4;
        u16 pk[4];
#pragma unroll
        for (int r = 0; r < 4; ++r) pk[r] = f2bf(acc[mi][ni][r]);
        *(uint2*)&base[mb] = *(uint2*)pk;
      }
  } else {
#pragma unroll
    for (int mi = 0; mi < 4; ++mi)
#pragma unroll
      for (int ni = 0; ni < 4; ++ni) {
        const int n = n0 + wn * 64 + ni * 16 + l15;
#pragma unroll
        for (int r = 0; r < 4; ++r) {
          const int m = m0 + wm * 64 + mi * 16 + g4 * 4 + r;
          float v = acc[mi][ni][r];
          if constexpr (sizeof(OutT) == 2) {
            C[(size_t)m * ldc + n] = (OutT)f2bf(v);
          } else {
            C[(size_t)m * ldc + n] = v;
          }
        }
      }
  }
}

// ---------------- flash attention: 128-q blocks, O^T accumulation ----------------
// Key points vs the 64-q version:
//  * 128 q/block halves staging+barrier+LDS-read cost per query (window 511
//    amortized over 2x queries); grid 512 = exactly 2 blocks/CU residency.
//  * O is accumulated TRANSPOSED: o = mfma(bv, ap) puts col = q = lane&15 --
//    the same per-lane mapping softmax state (m,l,alpha) lives in, so the
//    4-shuffle alpha broadcast and 4-shuffle l broadcast per step disappear.
//  * K/VT tiles staged via global_load_lds (swizzle folded into per-lane
//    SOURCE addresses; LDS base wave-uniform).
__global__ __launch_bounds__(256, 2) void attn_kernel(const u16* __restrict__ qk,
                                                      const u16* __restrict__ vt,
                                                      u16* __restrict__ out) {
  __shared__ __align__(16) u16 Ks[64 * 128];   // swizzled [kv][d]      16 KB
  __shared__ __align__(16) u16 VTs[128 * 64];  // swizzled [d][kv]      16 KB
  __shared__ __align__(16) u16 Ps[128 * 64];   // swizzled [q][kv]      16 KB (wave-private rows)
  const int q0 = blockIdx.x * 128;
  const int h = blockIdx.y;
  const int tid = threadIdx.x;
  const int w = tid >> 6;
  const int lane = tid & 63;
  const int l15 = lane & 15, g4 = lane >> 4, l7 = lane & 7;

  // Q fragments in registers: strips qs=0,1 -> q = q0 + w*32 + qs*16 + l15
  bf16x8 qf[2][4];
#pragma unroll
  for (int qs = 0; qs < 2; ++qs) {
    const u16* qrow = &qk[(size_t)(q0 + w * 32 + qs * 16 + l15) * QKW + h * HD + g4 * 8];
#pragma unroll
    for (int kk = 0; kk < 4; ++kk) qf[qs][kk] = *(const bf16x8*)&qrow[kk * 32];
  }

  float m_run[2] = {-1e30f, -1e30f}, l_run[2] = {0.f, 0.f};
  f32x4 o[2][8] = {};

  int lo = q0 - 255;
  int lo_blk = (lo < 0) ? 0 : (lo >> 6);
  int hi_blk = (q0 + 382) >> 6;
  if (hi_blk > 63) hi_blk = 63;
  const int extra = (lo_blk > 0) ? 1 : 0;     // kb=0 pre-pass for global kv cols
  const int nsteps = hi_blk - lo_blk + 1 + extra;

  for (int step = 0; step < nsteps; ++step) {
    const int kb = (extra && step == 0) ? 0 : (lo_blk + step - extra);
    const int kv0 = kb * 64;
    __syncthreads();   // prior step's Ks/VTs reads done
    // stage K tile [64 kv][128 d]: wave w rows w*16+p*4.., swizzled source chunk
#pragma unroll
    for (int p = 0; p < 4; ++p) {
      const int r = w * 16 + p * 4 + (lane >> 4);
      const u16* src = &qk[(size_t)(kv0 + r) * QKW + 2048 + h * HD + (((lane & 15) ^ (r & 15)) * 8)];
      async16(src, &Ks[(w * 16 + p * 4) * 128]);
    }
    // stage V^T tile [128 d][64 kv]: wave w rows w*32+p*8..
#pragma unroll
    for (int p = 0; p < 4; ++p) {
      const int r = w * 32 + p * 8 + (lane >> 3);
      const u16* src = &vt[(size_t)h * (HD * SEQ) + (size_t)r * SEQ + kv0 + (((lane & 7) ^ (r & 7)) * 8)];
      async16(src, &VTs[(w * 32 + p * 8) * 64]);
    }
    __syncthreads();

    // S^T = K @ Q^T : st[qs][t4] has row=kv (g4*4+reg), col=q (l15)
    f32x4 st[2][4] = {};
#pragma unroll
    for (int kk = 0; kk < 4; ++kk) {
      bf16x8 ak[4];
#pragma unroll
      for (int t4 = 0; t4 < 4; ++t4)
        ak[t4] = *(const bf16x8*)&Ks[(t4 * 16 + l15) * 128 + (((kk * 4 + g4) ^ l15) * 8)];
#pragma unroll
      for (int qs = 0; qs < 2; ++qs)
#pragma unroll
        for (int t4 = 0; t4 < 4; ++t4)
          st[qs][t4] = __builtin_amdgcn_mfma_f32_16x16x32_bf16(ak[t4], qf[qs][kk], st[qs][t4], 0, 0, 0);
    }

    // online softmax per q column; st reused as P
#pragma unroll
    for (int qs = 0; qs < 2; ++qs) {
      const int q = q0 + w * 32 + qs * 16 + l15;
      float cmax = -1e30f;
#pragma unroll
      for (int t4 = 0; t4 < 4; ++t4)
#pragma unroll
        for (int r = 0; r < 4; ++r) {
          int kv = kv0 + t4 * 16 + g4 * 4 + r;
          int dq = q - kv; if (dq < 0) dq = -dq;
          bool ok = (dq < 256) || (kv < 16);
          float s = ok ? st[qs][t4][r] * SCALE : -1e30f;
          st[qs][t4][r] = s;
          cmax = fmaxf(cmax, s);
        }
      cmax = fmaxf(cmax, __shfl_xor(cmax, 16, 64));
      cmax = fmaxf(cmax, __shfl_xor(cmax, 32, 64));
      float mnew = fmaxf(m_run[qs], cmax);
      float csum = 0.f;
#pragma unroll
      for (int t4 = 0; t4 < 4; ++t4)
#pragma unroll
        for (int r = 0; r < 4; ++r) {
          float p = __expf(st[qs][t4][r] - mnew);
          st[qs][t4][r] = p;
          csum += p;
        }
      csum += __shfl_xor(csum, 16, 64);
      csum += __shfl_xor(csum, 32, 64);
      float a = __expf(m_run[qs] - mnew);
      m_run[qs] = mnew;
      l_run[qs] = l_run[qs] * a + csum;

      // write P (bf16) into wave-private swizzled rows of Ps[q][kv]
#pragma unroll
      for (int t4 = 0; t4 < 4; ++t4) {
        u16 pk[4];
#pragma unroll
        for (int r = 0; r < 4; ++r) pk[r] = f2bf(st[qs][t4][r]);
        int c8 = t4 * 2 + (g4 >> 1);
        *(uint2*)&Ps[(w * 32 + qs * 16 + l15) * 64 + ((c8 ^ l7) * 8) + (g4 & 1) * 4] = *(uint2*)pk;
      }
      // rescale O^T (col = q = l15 -> alpha is per-lane, no broadcast)
#pragma unroll
      for (int nt = 0; nt < 8; ++nt)
#pragma unroll
        for (int r = 0; r < 4; ++r) o[qs][nt][r] *= a;
    }

    // O^T += V^T @ P^T : o = mfma(bv, ap) -> row=d, col=q (Ps wave-private, no barrier)
#pragma unroll
    for (int ks = 0; ks < 2; ++ks) {
      bf16x8 ap[2];
#pragma unroll
      for (int qs = 0; qs < 2; ++qs)
        ap[qs] = *(const bf16x8*)&Ps[(w * 32 + qs * 16 + l15) * 64 + (((ks * 4 + g4) ^ l7) * 8)];
#pragma unroll
      for (int nt = 0; nt < 8; ++nt) {
        bf16x8 bv = *(const bf16x8*)&VTs[(nt * 16 + l15) * 64 + (((ks * 4 + g4) ^ l7) * 8)];
#pragma unroll
        for (int qs = 0; qs < 2; ++qs)
          o[qs][nt] = __builtin_amdgcn_mfma_f32_16x16x32_bf16(bv, ap[qs], o[qs][nt], 0, 0, 0);
      }
    }
  }

  // finalize: O^T lane holds col q = l15, rows d = nt*16 + g4*4 + r -> packed uint2
#pragma unroll
  for (int qs = 0; qs < 2; ++qs) {
    if (q0 + w * 32 + qs * 16 < 16) continue;   // rows 0-15 written by attn_gred
    const int q = q0 + w * 32 + qs * 16 + l15;
    const float inv = 1.f / l_run[qs];
#pragma unroll
    for (int nt = 0; nt < 8; ++nt) {
      u16 pk[4];
#pragma unroll
      for (int r = 0; r < 4; ++r) pk[r] = f2bf(o[qs][nt][r] * inv);
      *(uint2*)&out[(size_t)q * HID + h * HD + nt * 16 + g4 * 4] = *(uint2*)pk;
    }
  }
}

// ---------------- global queries (q<16): split-KV VALU flash, partials ----------------
__global__ __launch_bounds__(256) void attn_global(const u16* __restrict__ qk,
                                                   const u16* __restrict__ vt,
                                                   float* __restrict__ Opart,
                                                   float* __restrict__ MLpart) {
  __shared__ __align__(16) u16 Ks[64 * 136];
  __shared__ __align__(16) u16 Vs[64 * 136];
  const int chunk = blockIdx.x, h = blockIdx.y;
  const int t = threadIdx.x;
  const int q = t >> 4, dg = t & 15;

  float qr[8];
  {
    bf16x8 v = *(const bf16x8*)&qk[(size_t)q * QKW + h * HD + dg * 8];
#pragma unroll
    for (int j = 0; j < 8; ++j) qr[j] = bf2f((u16)v[j]);
  }
  float m_run = -1e30f, l_run = 0.f, o[8] = {};
  const int kvbase = chunk * (SEQ / GQC);

  for (int st = 0; st < (SEQ / GQC) / 64; ++st) {
    const int kv0 = kvbase + st * 64;
    __syncthreads();
    // K rows
#pragma unroll
    for (int p = 0; p < 4; ++p) {
      int f = (t + p * 256) * 8;
      int r = f >> 7, c = f & 127;
      *(uint4*)&Ks[r * 136 + c] = *(const uint4*)&qk[(size_t)(kv0 + r) * QKW + 2048 + h * HD + c];
    }
    // V via transpose from VT
#pragma unroll
    for (int p = 0; p < 4; ++p) {
      int id = p * 256 + t;
      int d = id >> 3, c8 = id & 7;
      uint4 v = *(const uint4*)&vt[(size_t)h * (HD * SEQ) + (size_t)d * SEQ + kv0 + c8 * 8];
      const u16* pv16 = (const u16*)&v;
#pragma unroll
      for (int j = 0; j < 8; ++j) Vs[(c8 * 8 + j) * 136 + d] = pv16[j];
    }
    __syncthreads();
    for (int kv = 0; kv < 64; ++kv) {
      bf16x8 kr = *(const bf16x8*)&Ks[kv * 136 + dg * 8];
      float s = 0.f;
#pragma unroll
      for (int j = 0; j < 8; ++j) s += qr[j] * bf2f((u16)kr[j]);
      s += __shfl_xor(s, 1, 64); s += __shfl_xor(s, 2, 64);
      s += __shfl_xor(s, 4, 64); s += __shfl_xor(s, 8, 64);
      s *= SCALE;
      float mnew = fmaxf(m_run, s);
      float alpha = __expf(m_run - mnew);
      float p = __expf(s - mnew);
      m_run = mnew;
      l_run = l_run * alpha + p;
      bf16x8 vr = *(const bf16x8*)&Vs[kv * 136 + dg * 8];
#pragma unroll
      for (int j = 0; j < 8; ++j) o[j] = o[j] * alpha + p * bf2f((u16)vr[j]);
    }
  }
  float* op = &Opart[(((size_t)h * GQC + chunk) * 16 + q) * HD + dg * 8];
#pragma unroll
  for (int j = 0; j < 8; ++j) op[j] = o[j];
  if (dg == 0) {
    float* ml = &MLpart[(((size_t)h * GQC + chunk) * 16 + q) * 2];
    ml[0] = m_run; ml[1] = l_run;
  }
}

// ---------------- combine split-KV partials, write rows 0-15 of AttnO ----------------
__global__ __launch_bounds__(256) void attn_gred(const float* __restrict__ Opart,
                                                 const float* __restrict__ MLpart,
                                                 u16* __restrict__ out) {
  const int h = blockIdx.x;
  const int t = threadIdx.x;
  const int q = t >> 4, dg = t & 15;
  float M = -1e30f;
  for (int c = 0; c < GQC; ++c)
    M = fmaxf(M, MLpart[(((size_t)h * GQC + c) * 16 + q) * 2]);
  float L = 0.f, o[8] = {};
  for (int c = 0; c < GQC; ++c) {
    const float* ml = &MLpart[(((size_t)h * GQC + c) * 16 + q) * 2];
    float e = __expf(ml[0] - M);
    L += e * ml[1];
    const float* op = &Opart[(((size_t)h * GQC + c) * 16 + q) * HD + dg * 8];
#pragma unroll
    for (int j = 0; j < 8; ++j) o[j] += e * op[j];
  }
  float inv = 1.f / L;
  u16 tmp[8];
#pragma unroll
  for (int j = 0; j < 8; ++j) tmp[j] = f2bf(o[j] * inv);
  *(uint4*)&out[(size_t)q * HID + h * HD + dg * 8] = *(uint4*)tmp;
}

extern "C" void kernel_launch(void* const* d_in, const int* in_sizes, int n_in,
                              void* d_out, int out_size, void* d_ws, size_t ws_size,
                              hipStream_t stream) {
  const float* X  = (const float*)d_in[0];
  const float* Wq = (const float*)d_in[1];
  const float* Wk = (const float*)d_in[2];
  const float* Wv = (const float*)d_in[3];
  const float* Wo = (const float*)d_in[4];
  float* out = (float*)d_out;

  // workspace layout (96 MiB, lifetime-aliased):
  //  [0,16M):   Xbf   (dead after QKV GEMM)
  //  [16M,40M): Wcat  (dead after QKV GEMM) -> [16M,32M) AttnO, [32M,36M) Opart,
  //                                            [36M,~36.1M) MLpart
  //  [40M,72M): QK row-major [4096][4096] bf16 (Q | K)
  //  [72M,88M): VT[h][d][s] bf16 (written directly by QKV GEMM epilogue)
  //  [88M,96M): Wo^T bf16
  char* ws = (char*)d_ws;
  u16* Xbf    = (u16*)(ws);
  u16* Wcat   = (u16*)(ws + (size_t)(16 << 20));
  u16* AttnO  = (u16*)(ws + (size_t)(16 << 20));     // alias Wcat (post-GEMM)
  float* Opart  = (float*)(ws + (size_t)(32 << 20));
  float* MLpart = (float*)(ws + (size_t)(36 << 20));
  u16* QK     = (u16*)(ws + (size_t)(40 << 20));
  u16* VT     = (u16*)(ws + (size_t)(72 << 20));
  u16* Wot    = (u16*)(ws + (size_t)(88 << 20));

  // 1) X -> bf16
  cvt_f32_bf16<<<dim3(8192), dim3(256), 0, stream>>>(X, Xbf, (SEQ * HID) / 4);
  // 2) weight transposes (fp32 [k][n] -> bf16 [n][k]), one launch
  transpose_w4<<<dim3(32, 32, 4), 256, 0, stream>>>(Wq, Wk, Wv, Wo, Wcat, Wot);
  // 3) fused QKV GEMM: Q,K -> QK row-major; V -> VT transposed
  gemm_bt<u16, true><<<dim3(48, 32), 256, 0, stream>>>(Xbf, Wcat, QK, VT, HID, QKW);
  // 4) global queries: split-KV partials
  attn_global<<<dim3(GQC, NH), 256, 0, stream>>>(QK, VT, Opart, MLpart);
  // 5) local attention (128-q blocks; writes rows 16..4095)
  attn_kernel<<<dim3(SEQ / 128, NH), 256, 0, stream>>>(QK, VT, AttnO);
  // 6) combine global-query partials (writes rows 0..15)
  attn_gred<<<dim3(NH), 256, 0, stream>>>(Opart, MLpart, AttnO);
  // 7) output projection -> fp32 out
  gemm_bt<float, false><<<dim3(16, 32), 256, 0, stream>>>(AttnO, Wot, out, nullptr, HID, HID);
}

// Round 9
// 415.958 us; speedup vs baseline: 1.0383x; 1.0366x over previous
//
#include <hip/hip_runtime.h>
#include <stdint.h>

#define SEQ    4096
#define HID    2048
#define NQKV   6144
#define QKW    4096   // width of the QK row-major buffer (Q | K)
#define NH     16
#define HD     128
#define SCALE  0.08838834764831845f
#define GQC    32     // split-KV chunks for global-query path (128 kv each)

typedef unsigned short u16;
typedef __attribute__((ext_vector_type(8))) short bf16x8;
typedef __attribute__((ext_vector_type(4))) float f32x4;

__device__ __forceinline__ u16 f2bf(float f) {
  union { float f; unsigned u; } v; v.f = f;
  unsigned r = v.u + 0x7FFFu + ((v.u >> 16) & 1u);
  return (u16)(r >> 16);
}

__device__ __forceinline__ float bf2f(u16 b) {
  union { unsigned u; float f; } c; c.u = ((unsigned)b) << 16; return c.f;
}

__device__ __forceinline__ void async16(const u16* g, u16* l) {
  __builtin_amdgcn_global_load_lds(
      (const __attribute__((address_space(1))) unsigned int*)g,
      (__attribute__((address_space(3))) unsigned int*)l, 16, 0, 0);
}

// ---------------- prep: X->bf16 convert + 4 weight transposes + counter zero ----------------
// 1-D grid: [0, 8192) cvt blocks, [8192, 12288) transpose blocks.
// cnt lives in d_out (NOT ws): ws is exactly full and everything in it is
// written by prep or the QKV GEMM — R8 placed cnt inside Wcat and prep's own
// transpose writes clobbered it (rows 0-15 never reduced). d_out is untouched
// until the final out-projection, which overwrites it entirely.
__global__ __launch_bounds__(256) void prep(const float* __restrict__ X,
                                            const float* __restrict__ W0,
                                            const float* __restrict__ W1,
                                            const float* __restrict__ W2,
                                            const float* __restrict__ W3,
                                            u16* __restrict__ Xbf,
                                            u16* __restrict__ Wcat,
                                            u16* __restrict__ Wot,
                                            unsigned* __restrict__ cnt) {
  const int bx = blockIdx.x;
  const int t = threadIdx.x;
  if (bx == 0 && t < NH) cnt[t] = 0u;     // zero split-K completion counters
  if (bx < 8192) {
    int i = bx * 256 + t;
    float4 v = ((const float4*)X)[i];
    ushort4 o;
    o.x = f2bf(v.x); o.y = f2bf(v.y); o.z = f2bf(v.z); o.w = f2bf(v.w);
    ((ushort4*)Xbf)[i] = o;
    return;
  }
  __shared__ __align__(16) u16 Ts[64 * 68];
  const int b = bx - 8192;
  const int z = b >> 10;
  const int k0 = ((b >> 5) & 31) * 64;
  const int n0 = (b & 31) * 64;
  const float* W = (z == 0) ? W0 : (z == 1) ? W1 : (z == 2) ? W2 : W3;
  u16* Wt = (z < 3) ? (Wcat + (size_t)z * 2048 * 2048) : Wot;
#pragma unroll
  for (int p = 0; p < 4; ++p) {
    int f = (t + p * 256) * 4;
    int r = f >> 6, c = f & 63;            // r=k_local, c=n_local
    float4 v = *(const float4*)&W[(size_t)(k0 + r) * 2048 + n0 + c];
    ushort4 o; o.x = f2bf(v.x); o.y = f2bf(v.y); o.z = f2bf(v.z); o.w = f2bf(v.w);
    *(ushort4*)&Ts[r * 68 + c] = o;
  }
  __syncthreads();
#pragma unroll
  for (int p = 0; p < 4; ++p) {
    int g = (t + p * 256) * 4;
    int r = g >> 6, c = g & 63;            // r=n_local, c=k_local
    ushort4 o;
    o.x = Ts[(c + 0) * 68 + r];
    o.y = Ts[(c + 1) * 68 + r];
    o.z = Ts[(c + 2) * 68 + r];
    o.w = Ts[(c + 3) * 68 + r];
    *(ushort4*)&Wt[(size_t)(n0 + r) * 2048 + k0 + c] = o;
  }
}

// ---------------- GEMM: C[m][n] = sum_k A[m][k] * Bt[n][k]  (bf16 in, fp32 acc) ----------------
// 16x16x32 MFMA, 128x128 block, m97 [row][32] LDS layout (measured conflict floor).
// BK=64 via TWO [128][32] sub-buffers per operand: halves the vmcnt(0)+barrier
// drains per K while keeping the proven bank-conflict-free fragment reads.
template <typename OutT, bool WVT>
__global__ __launch_bounds__(256) void gemm_bt(const u16* __restrict__ A,
                                               const u16* __restrict__ B,
                                               OutT* __restrict__ C,
                                               u16* __restrict__ VTout,
                                               int K, int ldc) {
  __shared__ __align__(16) u16 As0[128 * 32];
  __shared__ __align__(16) u16 As1[128 * 32];
  __shared__ __align__(16) u16 Bs0[128 * 32];
  __shared__ __align__(16) u16 Bs1[128 * 32];
  const int m0 = blockIdx.y * 128;
  const int n0 = blockIdx.x * 128;
  const int tid = threadIdx.x;
  const int wid = tid >> 6;
  const int lane = tid & 63;
  const int wm = wid & 1, wn = wid >> 1;
  const int l15 = lane & 15, g4 = lane >> 4;

  const int srow = wid * 32 + (lane >> 2);
  const int scol = (lane & 3) * 8;

  f32x4 acc[4][4] = {};

  const u16* pa0 = &A[(size_t)(m0 + srow) * K + scol];
  const u16* pa1 = &A[(size_t)(m0 + srow + 16) * K + scol];
  const u16* pb0 = &B[(size_t)(n0 + srow) * K + scol];
  const u16* pb1 = &B[(size_t)(n0 + srow + 16) * K + scol];
  const int lo0 = (wid * 32) * 32, lo1 = (wid * 32 + 16) * 32;

  for (int kt = 0; kt < K; kt += 64) {
    __syncthreads();
    async16(pa0 + kt, &As0[lo0]);
    async16(pa1 + kt, &As0[lo1]);
    async16(pb0 + kt, &Bs0[lo0]);
    async16(pb1 + kt, &Bs0[lo1]);
    async16(pa0 + kt + 32, &As1[lo0]);
    async16(pa1 + kt + 32, &As1[lo1]);
    async16(pb0 + kt + 32, &Bs1[lo0]);
    async16(pb1 + kt + 32, &Bs1[lo1]);
    __syncthreads();
    {
      bf16x8 af[4], bfr[4];
#pragma unroll
      for (int i = 0; i < 4; ++i)
        af[i] = *(const bf16x8*)&As0[(wm * 64 + i * 16 + l15) * 32 + g4 * 8];
#pragma unroll
      for (int i = 0; i < 4; ++i)
        bfr[i] = *(const bf16x8*)&Bs0[(wn * 64 + i * 16 + l15) * 32 + g4 * 8];
#pragma unroll
      for (int mi = 0; mi < 4; ++mi)
#pragma unroll
        for (int ni = 0; ni < 4; ++ni)
          acc[mi][ni] = __builtin_amdgcn_mfma_f32_16x16x32_bf16(af[mi], bfr[ni], acc[mi][ni], 0, 0, 0);
    }
    {
      bf16x8 af[4], bfr[4];
#pragma unroll
      for (int i = 0; i < 4; ++i)
        af[i] = *(const bf16x8*)&As1[(wm * 64 + i * 16 + l15) * 32 + g4 * 8];
#pragma unroll
      for (int i = 0; i < 4; ++i)
        bfr[i] = *(const bf16x8*)&Bs1[(wn * 64 + i * 16 + l15) * 32 + g4 * 8];
#pragma unroll
      for (int mi = 0; mi < 4; ++mi)
#pragma unroll
        for (int ni = 0; ni < 4; ++ni)
          acc[mi][ni] = __builtin_amdgcn_mfma_f32_16x16x32_bf16(af[mi], bfr[ni], acc[mi][ni], 0, 0, 0);
    }
  }

  // C/D layout (m89): col = lane&15, row = (lane>>4)*4 + reg
  if (WVT && n0 >= QKW) {
#pragma unroll
    for (int mi = 0; mi < 4; ++mi)
#pragma unroll
      for (int ni = 0; ni < 4; ++ni) {
        const int nv = n0 - QKW + wn * 64 + ni * 16 + l15;
        const int hh = nv >> 7, dd = nv & 127;
        u16* base = &VTout[((size_t)hh * HD + dd) * SEQ];
        const int mb = m0 + wm * 64 + mi * 16 + g4 * 4;
        u16 pk[4];
#pragma unroll
        for (int r = 0; r < 4; ++r) pk[r] = f2bf(acc[mi][ni][r]);
        *(uint2*)&base[mb] = *(uint2*)pk;
      }
  } else {
#pragma unroll
    for (int mi = 0; mi < 4; ++mi)
#pragma unroll
      for (int ni = 0; ni < 4; ++ni) {
        const int n = n0 + wn * 64 + ni * 16 + l15;
#pragma unroll
        for (int r = 0; r < 4; ++r) {
          const int m = m0 + wm * 64 + mi * 16 + g4 * 4 + r;
          float v = acc[mi][ni][r];
          if constexpr (sizeof(OutT) == 2) {
            C[(size_t)m * ldc + n] = (OutT)f2bf(v);
          } else {
            C[(size_t)m * ldc + n] = v;
          }
        }
      }
  }
}

// ---------------- fused attention dispatch ----------------
// blockIdx.x < 32 : local 128-q flash blocks (window + global-kv), write rows 16..4095.
// blockIdx.x >= 32: split-KV chunk for global queries (q<16); the LAST chunk to
//                   finish per head (device-scope atomic counter in d_out) reduces
//                   all partials and writes rows 0..15. Counters zeroed in prep.
__global__ __launch_bounds__(256, 2) void attn_fused(const u16* __restrict__ qk,
                                                     const u16* __restrict__ vt,
                                                     u16* __restrict__ out,
                                                     float* __restrict__ Opart,
                                                     float* __restrict__ MLpart,
                                                     unsigned* __restrict__ cnt) {
  __shared__ __align__(16) u16 smem[24576];   // 48 KB, overlaid per path
  __shared__ unsigned lastflag;
  const int h = blockIdx.y;
  const int tid = threadIdx.x;
  const int lane = tid & 63;

  if (blockIdx.x < 32) {
    // ---------------- local path ----------------
    u16* Ks  = smem;            // [64 kv][128 d] swizzled, 16 KB
    u16* VTs = smem + 8192;     // [128 d][64 kv] swizzled, 16 KB
    u16* Ps  = smem + 16384;    // [128 q][64 kv] swizzled, wave-private rows, 16 KB
    const int q0 = blockIdx.x * 128;
    const int w = tid >> 6;
    const int l15 = lane & 15, g4 = lane >> 4, l7 = lane & 7;

    bf16x8 qf[2][4];
#pragma unroll
    for (int qs = 0; qs < 2; ++qs) {
      const u16* qrow = &qk[(size_t)(q0 + w * 32 + qs * 16 + l15) * QKW + h * HD + g4 * 8];
#pragma unroll
      for (int kk = 0; kk < 4; ++kk) qf[qs][kk] = *(const bf16x8*)&qrow[kk * 32];
    }

    float m_run[2] = {-1e30f, -1e30f}, l_run[2] = {0.f, 0.f};
    f32x4 o[2][8] = {};

    int lo = q0 - 255;
    int lo_blk = (lo < 0) ? 0 : (lo >> 6);
    int hi_blk = (q0 + 382) >> 6;
    if (hi_blk > 63) hi_blk = 63;
    const int extra = (lo_blk > 0) ? 1 : 0;
    const int nsteps = hi_blk - lo_blk + 1 + extra;

    for (int step = 0; step < nsteps; ++step) {
      const int kb = (extra && step == 0) ? 0 : (lo_blk + step - extra);
      const int kv0 = kb * 64;
      __syncthreads();
#pragma unroll
      for (int p = 0; p < 4; ++p) {
        const int r = w * 16 + p * 4 + (lane >> 4);
        const u16* src = &qk[(size_t)(kv0 + r) * QKW + 2048 + h * HD + (((lane & 15) ^ (r & 15)) * 8)];
        async16(src, &Ks[(w * 16 + p * 4) * 128]);
      }
#pragma unroll
      for (int p = 0; p < 4; ++p) {
        const int r = w * 32 + p * 8 + (lane >> 3);
        const u16* src = &vt[(size_t)h * (HD * SEQ) + (size_t)r * SEQ + kv0 + (((lane & 7) ^ (r & 7)) * 8)];
        async16(src, &VTs[(w * 32 + p * 8) * 64]);
      }
      __syncthreads();

      f32x4 st[2][4] = {};
#pragma unroll
      for (int kk = 0; kk < 4; ++kk) {
        bf16x8 ak[4];
#pragma unroll
        for (int t4 = 0; t4 < 4; ++t4)
          ak[t4] = *(const bf16x8*)&Ks[(t4 * 16 + l15) * 128 + (((kk * 4 + g4) ^ l15) * 8)];
#pragma unroll
        for (int qs = 0; qs < 2; ++qs)
#pragma unroll
          for (int t4 = 0; t4 < 4; ++t4)
            st[qs][t4] = __builtin_amdgcn_mfma_f32_16x16x32_bf16(ak[t4], qf[qs][kk], st[qs][t4], 0, 0, 0);
      }

#pragma unroll
      for (int qs = 0; qs < 2; ++qs) {
        const int q = q0 + w * 32 + qs * 16 + l15;
        float cmax = -1e30f;
#pragma unroll
        for (int t4 = 0; t4 < 4; ++t4)
#pragma unroll
          for (int r = 0; r < 4; ++r) {
            int kv = kv0 + t4 * 16 + g4 * 4 + r;
            int dq = q - kv; if (dq < 0) dq = -dq;
            bool ok = (dq < 256) || (kv < 16);
            float s = ok ? st[qs][t4][r] * SCALE : -1e30f;
            st[qs][t4][r] = s;
            cmax = fmaxf(cmax, s);
          }
        cmax = fmaxf(cmax, __shfl_xor(cmax, 16, 64));
        cmax = fmaxf(cmax, __shfl_xor(cmax, 32, 64));
        float mnew = fmaxf(m_run[qs], cmax);
        float csum = 0.f;
#pragma unroll
        for (int t4 = 0; t4 < 4; ++t4)
#pragma unroll
          for (int r = 0; r < 4; ++r) {
            float p = __expf(st[qs][t4][r] - mnew);
            st[qs][t4][r] = p;
            csum += p;
          }
        csum += __shfl_xor(csum, 16, 64);
        csum += __shfl_xor(csum, 32, 64);
        float a = __expf(m_run[qs] - mnew);
        m_run[qs] = mnew;
        l_run[qs] = l_run[qs] * a + csum;

#pragma unroll
        for (int t4 = 0; t4 < 4; ++t4) {
          u16 pk[4];
#pragma unroll
          for (int r = 0; r < 4; ++r) pk[r] = f2bf(st[qs][t4][r]);
          int c8 = t4 * 2 + (g4 >> 1);
          *(uint2*)&Ps[(w * 32 + qs * 16 + l15) * 64 + ((c8 ^ l7) * 8) + (g4 & 1) * 4] = *(uint2*)pk;
        }
#pragma unroll
        for (int nt = 0; nt < 8; ++nt)
#pragma unroll
          for (int r = 0; r < 4; ++r) o[qs][nt][r] *= a;
      }

#pragma unroll
      for (int ks = 0; ks < 2; ++ks) {
        bf16x8 ap[2];
#pragma unroll
        for (int qs = 0; qs < 2; ++qs)
          ap[qs] = *(const bf16x8*)&Ps[(w * 32 + qs * 16 + l15) * 64 + (((ks * 4 + g4) ^ l7) * 8)];
#pragma unroll
        for (int nt = 0; nt < 8; ++nt) {
          bf16x8 bv = *(const bf16x8*)&VTs[(nt * 16 + l15) * 64 + (((ks * 4 + g4) ^ l7) * 8)];
#pragma unroll
          for (int qs = 0; qs < 2; ++qs)
            o[qs][nt] = __builtin_amdgcn_mfma_f32_16x16x32_bf16(bv, ap[qs], o[qs][nt], 0, 0, 0);
        }
      }
    }

#pragma unroll
    for (int qs = 0; qs < 2; ++qs) {
      if (q0 + w * 32 + qs * 16 < 16) continue;   // rows 0-15 written by global path
      const int q = q0 + w * 32 + qs * 16 + l15;
      const float inv = 1.f / l_run[qs];
#pragma unroll
      for (int nt = 0; nt < 8; ++nt) {
        u16 pk[4];
#pragma unroll
        for (int r = 0; r < 4; ++r) pk[r] = f2bf(o[qs][nt][r] * inv);
        *(uint2*)&out[(size_t)q * HID + h * HD + nt * 16 + g4 * 4] = *(uint2*)pk;
      }
    }
    return;
  }

  // ---------------- global-query path (split-KV) ----------------
  {
    u16* Ks = smem;             // [64][136]
    u16* Vs = smem + 8704;      // [64][136]
    const int chunk = blockIdx.x - 32;
    const int t = tid;
    const int q = t >> 4, dg = t & 15;

    float qr[8];
    {
      bf16x8 v = *(const bf16x8*)&qk[(size_t)q * QKW + h * HD + dg * 8];
#pragma unroll
      for (int j = 0; j < 8; ++j) qr[j] = bf2f((u16)v[j]);
    }
    float m_run = -1e30f, l_run = 0.f, o[8] = {};
    const int kvbase = chunk * (SEQ / GQC);

    for (int st = 0; st < (SEQ / GQC) / 64; ++st) {
      const int kv0 = kvbase + st * 64;
      __syncthreads();
#pragma unroll
      for (int p = 0; p < 4; ++p) {
        int f = (t + p * 256) * 8;
        int r = f >> 7, c = f & 127;
        *(uint4*)&Ks[r * 136 + c] = *(const uint4*)&qk[(size_t)(kv0 + r) * QKW + 2048 + h * HD + c];
      }
#pragma unroll
      for (int p = 0; p < 4; ++p) {
        int id = p * 256 + t;
        int d = id >> 3, c8 = id & 7;
        uint4 v = *(const uint4*)&vt[(size_t)h * (HD * SEQ) + (size_t)d * SEQ + kv0 + c8 * 8];
        const u16* pv16 = (const u16*)&v;
#pragma unroll
        for (int j = 0; j < 8; ++j) Vs[(c8 * 8 + j) * 136 + d] = pv16[j];
      }
      __syncthreads();
      for (int kv = 0; kv < 64; ++kv) {
        bf16x8 kr = *(const bf16x8*)&Ks[kv * 136 + dg * 8];
        float s = 0.f;
#pragma unroll
        for (int j = 0; j < 8; ++j) s += qr[j] * bf2f((u16)kr[j]);
        s += __shfl_xor(s, 1, 64); s += __shfl_xor(s, 2, 64);
        s += __shfl_xor(s, 4, 64); s += __shfl_xor(s, 8, 64);
        s *= SCALE;
        float mnew = fmaxf(m_run, s);
        float alpha = __expf(m_run - mnew);
        float p = __expf(s - mnew);
        m_run = mnew;
        l_run = l_run * alpha + p;
        bf16x8 vr = *(const bf16x8*)&Vs[kv * 136 + dg * 8];
#pragma unroll
        for (int j = 0; j < 8; ++j) o[j] = o[j] * alpha + p * bf2f((u16)vr[j]);
      }
    }
    float* op = &Opart[(((size_t)h * GQC + chunk) * 16 + q) * HD + dg * 8];
#pragma unroll
    for (int j = 0; j < 8; ++j) op[j] = o[j];
    if (dg == 0) {
      float* ml = &MLpart[(((size_t)h * GQC + chunk) * 16 + q) * 2];
      ml[0] = m_run; ml[1] = l_run;
    }

    // last-chunk-done reduction for this head
    __syncthreads();                 // all waves' stores drained (vmcnt 0 before barrier)
    if (t == 0) {
      __threadfence();               // release: flush XCD L2 to coherence point
      lastflag = (atomicAdd(&cnt[h], 1u) == GQC - 1) ? 1u : 0u;
    }
    __syncthreads();
    if (lastflag) {
      __threadfence();               // acquire: invalidate stale cached partials
      float M = -1e30f;
      for (int c = 0; c < GQC; ++c)
        M = fmaxf(M, MLpart[(((size_t)h * GQC + c) * 16 + q) * 2]);
      float L = 0.f, oo[8] = {};
      for (int c = 0; c < GQC; ++c) {
        const float* ml = &MLpart[(((size_t)h * GQC + c) * 16 + q) * 2];
        float e = __expf(ml[0] - M);
        L += e * ml[1];
        const float* opc = &Opart[(((size_t)h * GQC + c) * 16 + q) * HD + dg * 8];
#pragma unroll
        for (int j = 0; j < 8; ++j) oo[j] += e * opc[j];
      }
      float inv = 1.f / L;
      u16 tmp[8];
#pragma unroll
      for (int j = 0; j < 8; ++j) tmp[j] = f2bf(oo[j] * inv);
      *(uint4*)&out[(size_t)q * HID + h * HD + dg * 8] = *(uint4*)tmp;
    }
  }
}

extern "C" void kernel_launch(void* const* d_in, const int* in_sizes, int n_in,
                              void* d_out, int out_size, void* d_ws, size_t ws_size,
                              hipStream_t stream) {
  const float* X  = (const float*)d_in[0];
  const float* Wq = (const float*)d_in[1];
  const float* Wk = (const float*)d_in[2];
  const float* Wv = (const float*)d_in[3];
  const float* Wo = (const float*)d_in[4];
  float* out = (float*)d_out;

  // workspace layout (96 MiB, lifetime-aliased):
  //  [0,16M):   Xbf   (dead after QKV GEMM)
  //  [16M,40M): Wcat  (dead after QKV GEMM) -> [16M,32M) AttnO, [32M,36M) Opart,
  //                                            [36M,36M+64K) MLpart
  //  [40M,72M): QK row-major [4096][4096] bf16 (Q | K)
  //  [72M,88M): VT[h][d][s] bf16 (written directly by QKV GEMM epilogue)
  //  [88M,96M): Wo^T bf16
  //  cnt -> first 64 B of d_out (ws is full; d_out untouched until final GEMM,
  //         which overwrites it entirely after attn_fused is done with cnt).
  char* ws = (char*)d_ws;
  u16* Xbf    = (u16*)(ws);
  u16* Wcat   = (u16*)(ws + (size_t)(16 << 20));
  u16* AttnO  = (u16*)(ws + (size_t)(16 << 20));     // alias Wcat (post-GEMM)
  float* Opart  = (float*)(ws + (size_t)(32 << 20));
  float* MLpart = (float*)(ws + (size_t)(36 << 20));
  unsigned* cnt = (unsigned*)d_out;
  u16* QK     = (u16*)(ws + (size_t)(40 << 20));
  u16* VT     = (u16*)(ws + (size_t)(72 << 20));
  u16* Wot    = (u16*)(ws + (size_t)(88 << 20));

  // 1) prep: X->bf16, weight transposes, counter zero (one dispatch)
  prep<<<dim3(12288), 256, 0, stream>>>(X, Wq, Wk, Wv, Wo, Xbf, Wcat, Wot, cnt);
  // 2) fused QKV GEMM: Q,K -> QK row-major; V -> VT transposed
  gemm_bt<u16, true><<<dim3(48, 32), 256, 0, stream>>>(Xbf, Wcat, QK, VT, HID, QKW);
  // 3) fused attention: local flash + global-query split-KV + last-block reduce
  attn_fused<<<dim3(32 + GQC, NH), 256, 0, stream>>>(QK, VT, AttnO, Opart, MLpart, cnt);
  // 4) output projection -> fp32 out (overwrites cnt bytes with real output)
  gemm_bt<float, false><<<dim3(16, 32), 256, 0, stream>>>(AttnO, Wot, out, nullptr, HID, HID);
}